// Round 2
// baseline (253.354 us; speedup 1.0000x reference)
//
#include <hip/hip_runtime.h>

typedef _Float16 f16;
typedef f16 f16x4 __attribute__((ext_vector_type(4)));
typedef f16 f16x8 __attribute__((ext_vector_type(8)));
typedef __fp16 h16x2 __attribute__((ext_vector_type(2)));
typedef float floatx4 __attribute__((ext_vector_type(4)));

#define LDT 72  // transpose-kernel tile stride (f16), 2-way reads are free
#define LDE 136 // gemm1 epilogue V-transpose tile stride (16B-aligned rows for uint4)
#define QSCALE 11.5415603271117f  // 8 * log2(e): score computed in log2 domain

// direct global->LDS DMA, 16B per lane. LDS dest is WAVE-UNIFORM base;
// HW scatters lane i at base + i*16B. Global src is per-lane.
__device__ __forceinline__ void gld16(const void* g, void* l) {
  __builtin_amdgcn_global_load_lds((const __attribute__((address_space(1))) unsigned int*)g,
                                   (__attribute__((address_space(3))) unsigned int*)l,
                                   16, 0, 0);
}

// x [8192,768] fp32 -> f16, vectorized 32B-in / 16B-out per thread (memory-bound)
__global__ __launch_bounds__(256) void cvt_f32_f16(const float* __restrict__ in,
                                                   f16* __restrict__ out) {
  size_t i = ((size_t)blockIdx.x * 256 + threadIdx.x) * 8;
  float4 v0 = *(const float4*)(in + i);
  float4 v1 = *(const float4*)(in + i + 4);
  f16x8 h = {(f16)v0.x, (f16)v0.y, (f16)v0.z, (f16)v0.w,
             (f16)v1.x, (f16)v1.y, (f16)v1.z, (f16)v1.w};
  *(f16x8*)(out + i) = h;
}

// W [K][N] fp32 -> Wt [N][K] fp16, 64x64 tiles via LDS: coalesced both sides
__global__ __launch_bounds__(256) void transpose_f32_f16_tiled(const float* __restrict__ in,
                                                               f16* __restrict__ out,
                                                               int K, int N) {
  __shared__ f16 tile[64][LDT];
  int k0 = blockIdx.x * 64, n0 = blockIdx.y * 64;
  int tid = threadIdx.x;
  int r = tid >> 4, c4 = (tid & 15) * 4;
  for (int p = 0; p < 4; ++p) {
    int rr = r + p * 16;
    float4 v = *(const float4*)(in + (size_t)(k0 + rr) * N + n0 + c4);
    tile[c4 + 0][rr] = (f16)v.x;
    tile[c4 + 1][rr] = (f16)v.y;
    tile[c4 + 2][rr] = (f16)v.z;
    tile[c4 + 3][rr] = (f16)v.w;
  }
  __syncthreads();
  int rn = tid >> 3, ck = (tid & 7) * 8;
  for (int p = 0; p < 2; ++p) {
    int rr = rn + p * 32;
    *(uint4*)(out + (size_t)(n0 + rr) * K + k0 + ck) = *(const uint4*)(&tile[rr][ck]);
  }
}

// qkv = x16 @ WqkvT^T (both f16, fp32 acc), global_load_lds staging.
__global__ __launch_bounds__(256) void gemm1_qkv(const f16* __restrict__ A,
                                                 const f16* __restrict__ Bt,
                                                 f16* __restrict__ q16, f16* __restrict__ k16,
                                                 f16* __restrict__ vt) {
  __shared__ f16 smem[17408];
  f16* As = smem;
  f16* Bs = smem + 8192;
  int tid = threadIdx.x;
  int lane = tid & 63, wid = tid >> 6;
  int quad = lane >> 4, l16 = lane & 15;
  int wy = wid >> 1, wx = wid & 1;
  int m0 = blockIdx.x * 128, n0 = blockIdx.y * 128;
  int gr = lane >> 3, gc = (lane & 7) * 8;
  floatx4 acc[4][4] = {};
  for (int k0 = 0; k0 < 768; k0 += 64) {
    for (int p = 0; p < 4; ++p) {
      int c = wid * 4 + p;
      int row = c * 8 + gr;
      gld16(A + (size_t)(m0 + row) * 768 + k0 + gc, As + c * 512);
      gld16(Bt + (size_t)(n0 + row) * 768 + k0 + gc, Bs + c * 512);
    }
    __syncthreads();
    for (int kk = 0; kk < 64; kk += 32) {
      f16x8 af[4], bfr[4];
      for (int i = 0; i < 4; ++i)
        af[i] = *(const f16x8*)(As + (wy * 64 + i * 16 + l16) * 64 + kk + quad * 8);
      for (int j = 0; j < 4; ++j)
        bfr[j] = *(const f16x8*)(Bs + (wx * 64 + j * 16 + l16) * 64 + kk + quad * 8);
      for (int i = 0; i < 4; ++i)
        for (int j = 0; j < 4; ++j)
          acc[i][j] = __builtin_amdgcn_mfma_f32_16x16x32_f16(af[i], bfr[j], acc[i][j], 0, 0, 0);
    }
    __syncthreads();
  }
  int b = m0 >> 11, t0 = m0 & 2047;
  if (n0 < 1536) {
    for (int i = 0; i < 4; ++i)
      for (int j = 0; j < 4; ++j)
        for (int r = 0; r < 4; ++r) {
          int t = t0 + wy * 64 + i * 16 + quad * 4 + r;
          int col = n0 + wx * 64 + j * 16 + l16;
          float a = acc[i][j][r];
          if (col < 768) {
            int h = col >> 6, d = col & 63;
            q16[((size_t)(b * 12 + h)) * 131072 + (size_t)t * 64 + d] = (f16)(a * QSCALE);
          } else {
            int c = col - 768;
            int h = c >> 6, d = c & 63;
            k16[((size_t)(b * 12 + h)) * 131072 + (size_t)t * 64 + d] = (f16)a;
          }
        }
  } else {
    f16* Vtile = smem;  // 128*LDE = 34816 B
    int h0 = (n0 - 1536) >> 6;
    for (int i = 0; i < 4; ++i)
      for (int j = 0; j < 4; ++j) {
        int cl = wx * 64 + j * 16 + l16;
        int rl = wy * 64 + i * 16 + quad * 4;
        for (int r = 0; r < 4; ++r)
          Vtile[cl * LDE + rl + r] = (f16)acc[i][j][r];
      }
    __syncthreads();
    int u = tid & 15;
    for (int p = 0; p < 8; ++p) {
      int c = (tid >> 4) + p * 16;
      *(uint4*)(vt + ((size_t)(b * 12 + h0 + (c >> 6))) * 131072 +
                (size_t)(c & 63) * 2048 + t0 + u * 8) =
          *(const uint4*)(Vtile + c * LDE + u * 8);
    }
  }
}

// C[M,N](fp32) = A[M,K](f16) * Bt[N,K]^T(f16), global_load_lds staging
__global__ __launch_bounds__(256) void gemm_bt_f16(const f16* __restrict__ A,
                                                   const f16* __restrict__ Bt,
                                                   float* __restrict__ C,
                                                   int M, int N, int K) {
  __shared__ f16 As[8192];
  __shared__ f16 Bs[8192];
  int tid = threadIdx.x;
  int lane = tid & 63, wid = tid >> 6;
  int quad = lane >> 4, l16 = lane & 15;
  int wy = wid >> 1, wx = wid & 1;
  int m0 = blockIdx.x * 128, n0 = blockIdx.y * 128;
  int gr = lane >> 3, gc = (lane & 7) * 8;
  floatx4 acc[4][4] = {};
  for (int k0 = 0; k0 < K; k0 += 64) {
    for (int p = 0; p < 4; ++p) {
      int c = wid * 4 + p;
      int row = c * 8 + gr;
      gld16(A + (size_t)(m0 + row) * K + k0 + gc, As + c * 512);
      gld16(Bt + (size_t)(n0 + row) * K + k0 + gc, Bs + c * 512);
    }
    __syncthreads();
    for (int kk = 0; kk < 64; kk += 32) {
      f16x8 af[4], bfr[4];
      for (int i = 0; i < 4; ++i)
        af[i] = *(const f16x8*)(As + (wy * 64 + i * 16 + l16) * 64 + kk + quad * 8);
      for (int j = 0; j < 4; ++j)
        bfr[j] = *(const f16x8*)(Bs + (wx * 64 + j * 16 + l16) * 64 + kk + quad * 8);
      for (int i = 0; i < 4; ++i)
        for (int j = 0; j < 4; ++j)
          acc[i][j] = __builtin_amdgcn_mfma_f32_16x16x32_f16(af[i], bfr[j], acc[i][j], 0, 0, 0);
    }
    __syncthreads();
  }
  for (int i = 0; i < 4; ++i) {
    int row = m0 + wy * 64 + i * 16 + quad * 4;
    for (int j = 0; j < 4; ++j) {
      int col = n0 + wx * 64 + j * 16 + l16;
      for (int r = 0; r < 4; ++r)
        C[(size_t)(row + r) * N + col] = acc[i][j][r];
    }
  }
}

// Flash attention v9: 4 waves x 32 q-rows (2 groups), halves LDS read traffic
// per q-row vs v8 (each K/V fragment feeds 2 MFMAs). Double-buffered LDS (64KB)
// with global_load_lds staging on PRE-SWIZZLED global addresses (XOR involution
// matches read side). T3-minimal pipeline: issue next-tile gld16 before compute,
// one barrier per kt. Buffers statically named per phase (kt unrolled x2) so
// alias analysis keeps ds_reads free of conservative vmcnt waits.
__global__ __launch_bounds__(256, 1) void flash_attn(const f16* __restrict__ q16,
                                                     const f16* __restrict__ k16,
                                                     const f16* __restrict__ vT,
                                                     f16* __restrict__ y) {
  __shared__ f16 KsA[128 * 64];
  __shared__ f16 VtA[64 * 128];
  __shared__ f16 KsB[128 * 64];
  __shared__ f16 VtB[64 * 128];
  const int T = 2048;
  // XCD-locality remap: all 16 q-tiles of a head land on one XCD's L2
  int xcd = blockIdx.x & 7, yb = blockIdx.x >> 3;  // yb in [0,96)
  int bh = xcd * 6 + (yb >> 4);
  int qt = yb & 15;
  int b = bh / 12, h = bh - b * 12;
  int tid = threadIdx.x;
  int lane = tid & 63, wid = tid >> 6;             // wid in [0,4)
  int quad = lane >> 4, l16 = lane & 15;
  size_t hb = (size_t)bh * T * 64;

  // K staging: chunk c=wid*4+p covers rows c*8..c*8+7. Lane L -> dest row
  // c*8+(L>>3), dest 8-f16 col chunk L&7; source col chunk is XOR-swizzled.
  int kr = lane >> 3;
  int kcc = ((lane & 7) ^ kr) * 8;
  const f16* kbase = k16 + hb + (size_t)(wid * 32 + kr) * 64 + kcc;
  // V staging: chunk c=wid*4+p covers d rows c*4..c*4+3 (row len 128 f16).
  const f16* vbase0;
  const f16* vbase1;
  const f16* vbase2;
  const f16* vbase3;
  {
    int lr = lane >> 4, lc = lane & 15;
    vbase0 = vT + hb + (size_t)(wid * 16 + 0 + lr) * T + ((lc ^ (0 + lr)) * 8);
    vbase1 = vT + hb + (size_t)(wid * 16 + 4 + lr) * T + ((lc ^ (4 + lr)) * 8);
    vbase2 = vT + hb + (size_t)(wid * 16 + 8 + lr) * T + ((lc ^ (8 + lr)) * 8);
    vbase3 = vT + hb + (size_t)(wid * 16 + 12 + lr) * T + ((lc ^ (12 + lr)) * 8);
  }

#define STAGE(KD, VD, ktn)                                              \
  do {                                                                  \
    const f16* kp_ = kbase + (size_t)(ktn) * 8192;                      \
    gld16(kp_ + 0 * 512, (KD) + (wid * 4 + 0) * 512);                   \
    gld16(kp_ + 1 * 512, (KD) + (wid * 4 + 1) * 512);                   \
    gld16(kp_ + 2 * 512, (KD) + (wid * 4 + 2) * 512);                   \
    gld16(kp_ + 3 * 512, (KD) + (wid * 4 + 3) * 512);                   \
    gld16(vbase0 + (ktn) * 128, (VD) + (wid * 4 + 0) * 512);            \
    gld16(vbase1 + (ktn) * 128, (VD) + (wid * 4 + 1) * 512);            \
    gld16(vbase2 + (ktn) * 128, (VD) + (wid * 4 + 2) * 512);            \
    gld16(vbase3 + (ktn) * 128, (VD) + (wid * 4 + 3) * 512);            \
  } while (0)

  // Q fragments: 32 q-rows per wave (2 groups of 16), B-operand m = l16
  f16x8 qf[2][2];
#pragma unroll
  for (int g = 0; g < 2; ++g) {
    size_t qrow = hb + (size_t)(qt * 128 + wid * 32 + g * 16 + l16) * 64 + quad * 8;
    qf[g][0] = *(const f16x8*)(q16 + qrow);
    qf[g][1] = *(const f16x8*)(q16 + qrow + 32);
  }
  f16x4 ones4;
  for (int e = 0; e < 4; ++e) ones4[e] = (f16)1.0f;

  float m_i[2] = {-1e30f, -1e30f}, l_i[2] = {0.f, 0.f};
  floatx4 o[2][4] = {};  // O^T per group: dn = i*16 + quad*4 + reg, m = l16

#define COMPUTE(KC, VC)                                                            \
  do {                                                                             \
    floatx4 sf[2][8] = {};                                                         \
    _Pragma("unroll") for (int kk = 0; kk < 2; ++kk)                               \
        _Pragma("unroll") for (int i = 0; i < 8; ++i) {                            \
      f16x8 kf = *(const f16x8*)((KC) + (i * 16 + l16) * 64 +                      \
                                 (((kk * 4 + quad) ^ (l16 & 7)) * 8));             \
      sf[0][i] = __builtin_amdgcn_mfma_f32_16x16x32_f16(kf, qf[0][kk], sf[0][i], 0, 0, 0); \
      sf[1][i] = __builtin_amdgcn_mfma_f32_16x16x32_f16(kf, qf[1][kk], sf[1][i], 0, 0, 0); \
    }                                                                              \
    f16x4 pf[2][8];                                                                \
    _Pragma("unroll") for (int g = 0; g < 2; ++g) {                                \
      float mx = fmaxf(fmaxf(sf[g][0][0], sf[g][0][1]), fmaxf(sf[g][0][2], sf[g][0][3])); \
      _Pragma("unroll") for (int i = 1; i < 8; ++i)                                \
          mx = fmaxf(mx, fmaxf(fmaxf(sf[g][i][0], sf[g][i][1]),                    \
                               fmaxf(sf[g][i][2], sf[g][i][3])));                  \
      mx = fmaxf(mx, __shfl_xor(mx, 16));                                          \
      mx = fmaxf(mx, __shfl_xor(mx, 32));                                          \
      float m_new = fmaxf(m_i[g], mx);                                             \
      float alpha = exp2f(m_i[g] - m_new);                                         \
      m_i[g] = m_new;                                                              \
      _Pragma("unroll") for (int i = 0; i < 4; ++i) o[g][i] *= alpha;              \
      _Pragma("unroll") for (int i = 0; i < 8; ++i) {                              \
        union { h16x2 hh; f16 ff[2]; } a2, b2;                                     \
        a2.hh = __builtin_amdgcn_cvt_pkrtz(sf[g][i][0] - m_new, sf[g][i][1] - m_new); \
        b2.hh = __builtin_amdgcn_cvt_pkrtz(sf[g][i][2] - m_new, sf[g][i][3] - m_new); \
        f16x4 uu = {a2.ff[0], a2.ff[1], b2.ff[0], b2.ff[1]};                       \
        pf[g][i] = __builtin_elementwise_exp2(uu);                                 \
      }                                                                            \
      floatx4 rs = {0.f, 0.f, 0.f, 0.f};                                           \
      _Pragma("unroll") for (int si = 0; si < 8; ++si)                             \
          rs = __builtin_amdgcn_mfma_f32_16x16x16f16(ones4, pf[g][si], rs, 0, 0, 0); \
      l_i[g] = l_i[g] * alpha + rs[0];                                             \
    }                                                                              \
    _Pragma("unroll") for (int i = 0; i < 4; ++i)                                  \
        _Pragma("unroll") for (int si = 0; si < 8; ++si) {                         \
      int cch = si * 2 + (quad >> 1);                                              \
      f16x4 vf = *(const f16x4*)((VC) + (i * 16 + l16) * 128 + ((cch ^ l16) * 8) + \
                                 (quad & 1) * 4);                                  \
      o[0][i] = __builtin_amdgcn_mfma_f32_16x16x16f16(vf, pf[0][si], o[0][i], 0, 0, 0); \
      o[1][i] = __builtin_amdgcn_mfma_f32_16x16x16f16(vf, pf[1][si], o[1][i], 0, 0, 0); \
    }                                                                              \
  } while (0)

  STAGE(KsA, VtA, 0);
  __syncthreads();  // drains vmcnt: tile 0 staged

#pragma unroll 1
  for (int kt2 = 0; kt2 < 8; ++kt2) {
    STAGE(KsB, VtB, 2 * kt2 + 1);   // async prefetch, hides under compute
    COMPUTE(KsA, VtA);
    __syncthreads();                // drains vmcnt: tile 2*kt2+1 staged
    if (kt2 < 7) STAGE(KsA, VtA, 2 * kt2 + 2);
    COMPUTE(KsB, VtB);
    if (kt2 < 7) __syncthreads();
  }

  // epilogue: O^T[dn][m] -> y[b, t, h*64+dn]
#pragma unroll
  for (int g = 0; g < 2; ++g) {
    float invl = 1.0f / l_i[g];
    int t = qt * 128 + wid * 32 + g * 16 + l16;
    size_t off = ((size_t)(b * T + t)) * 768 + h * 64;
    for (int i = 0; i < 4; ++i)
      for (int r = 0; r < 4; ++r)
        y[off + i * 16 + quad * 4 + r] = (f16)(o[g][i][r] * invl);
  }
#undef STAGE
#undef COMPUTE
}

extern "C" void kernel_launch(void* const* d_in, const int* in_sizes, int n_in,
                              void* d_out, int out_size, void* d_ws, size_t ws_size,
                              hipStream_t stream) {
  const float* x     = (const float*)d_in[0];  // [4,2048,768] fp32
  const float* Wqkv  = (const float*)d_in[1];  // [768,2304] fp32
  const float* Wproj = (const float*)d_in[2];  // [768,768] fp32
  float* out = (float*)d_out;                  // [4,2048,768] fp32
  char* ws = (char*)d_ws;
  f16* q16    = (f16*)ws;                  // 8192*768*2 = 12,582,912 B each
  f16* k16    = (f16*)(ws + 12582912);
  f16* vT16   = (f16*)(ws + 25165824);
  f16* y16    = (f16*)(ws + 37748736);
  f16* WqkvT  = (f16*)(ws + 50331648);     // 2304*768*2 = 3,538,944 B
  f16* WprojT = (f16*)(ws + 53870592);     //  768*768*2 = 1,179,648 B
  // x16 lives in the y16 slot: consumed by gemm1 before flash_attn writes y16
  f16* x16 = y16;

  cvt_f32_f16<<<3072, 256, 0, stream>>>(x, x16);
  transpose_f32_f16_tiled<<<dim3(12, 36), 256, 0, stream>>>(Wqkv, WqkvT, 768, 2304);
  transpose_f32_f16_tiled<<<dim3(12, 12), 256, 0, stream>>>(Wproj, WprojT, 768, 768);
  gemm1_qkv<<<dim3(64, 18), 256, 0, stream>>>(x16, WqkvT, q16, k16, vT16);
  flash_attn<<<768, 256, 0, stream>>>(q16, k16, vT16, y16);
  gemm_bt_f16<<<dim3(64, 6), 256, 0, stream>>>(y16, WprojT, out, 8192, 768, 768);
}